// Round 1
// baseline (1219.244 us; speedup 1.0000x reference)
//
#include <hip/hip_runtime.h>

// MaxUnpooling2D scatter-add — round 5: nested two-pass radix partition.
//
// R4 post-mortem: p3_place still wrote 968 MB for a 268 MB pairs array
// (3.5x amplification). Root cause: open-line pressure per XCD =
// blocks/XCD (32) x active buckets/block (2^24 span / 2^14 bucket = 1024)
// x 128 B = 4 MB == the whole per-XCD L2, thrashed by the streaming
// mask/updates reads. Active-buckets is fixed by the mask value range,
// not CHUNK, so no single-pass tuning fixes it.
//
// R5: two nested passes.
//   p3a: partition by COARSE bucket (2^16 floats). 256 runs/block ->
//        1 MB/XCD open lines, fits L2 -> full-line evictions.
//   p3b: each coarse bucket == exactly 4 fine buckets (2^14 | 2^16).
//        One block owns one coarse bucket -> private LDS tickets,
//        4 long runs, single-XCD write frontier. Wave-aggregated
//        (2-ballot match on f&3, leader-only atomic) to kill LDS
//        same-address serialization.
//   Pass-1 pairs live in the OUTPUT TAIL [OUT_WIN, OUT_TOTAL) (352 MB
//        >= 268 MB); tail is zeroed AFTER p3b consumed it. ws holds only
//        the pass-2 (fine-sorted) pairs -> ws requirement unchanged.
//   Fine bucket totals come from one global-atomic fhist in p1 (replaces
//        the 2.9 MB per-block fine hist + segsum/expand machinery; fine
//        per-block offsets are no longer needed since p3b owns buckets).

typedef float floatx4 __attribute__((ext_vector_type(4)));

constexpr int FLAT_IN   = 1 << 22;                 // 4,194,304
constexpr int N_ELEMS   = 8 * FLAT_IN;             // 33,554,432
constexpr int OUT_WIN   = 7 * FLAT_IN + (1 << 24); // 46,137,344
constexpr int OUT_TOTAL = 134217728;

constexpr int FB_SHIFT = 14;                  // fine bucket: 16K floats (64 KB LDS win)
constexpr int BKT_SIZE = 1 << FB_SHIFT;
constexpr int NBF      = OUT_WIN >> FB_SHIFT; // 2816 = 11*256
constexpr int CB_SHIFT = 16;                  // coarse bucket: 64K floats
constexpr int NBC      = OUT_WIN >> CB_SHIFT; // 704  (4 fine per coarse, nested)
constexpr int NBC_PAD  = 768;                 // 3*256 for scan kernels

constexpr int PBLOCK   = 1024;                // threads, partition kernels
constexpr int CHUNK    = 131072;              // elems per p1/p3a block
constexpr int NBLK     = N_ELEMS / CHUNK;     // 256
constexpr int ITERS    = CHUNK / (4 * PBLOCK);// 32
constexpr int SEGS     = 8;
constexpr int SEG_ROWS = NBLK / SEGS;         // 32

// ---- workspace layout (bytes); pass-1 pairs live in out[OUT_WIN..] ----
constexpr size_t WS_PAIRS  = 0;                                   // int2[N_ELEMS] fine-sorted = 268,435,456
constexpr size_t WS_HISTC  = 268435456;                           // int[NBLK*NBC_PAD] = 786,432
constexpr size_t WS_SEGC   = WS_HISTC + (size_t)NBLK * NBC_PAD * 4;
constexpr size_t WS_BBC    = WS_SEGC + (size_t)SEGS * NBC_PAD * 4;  // int[NBC_PAD+1]
constexpr size_t WS_FH     = WS_BBC + 3328;                         // int[NBF] (16B aligned)
constexpr size_t WS_BBF    = WS_FH + (size_t)NBF * 4;               // int[NBF+1]
constexpr size_t WS_NEEDED = WS_BBF + (size_t)(NBF + 1) * 4;

// ---------------- K0: zero a float4 range (nontemporal) ----------------
__global__ __launch_bounds__(256) void zero_kernel(floatx4* __restrict__ p, int n4) {
  int i = blockIdx.x * 256 + threadIdx.x;
  int stride = gridDim.x * 256;
  floatx4 z = {0.f, 0.f, 0.f, 0.f};
  for (; i < n4; i += stride) __builtin_nontemporal_store(z, p + i);
}

// ---------------- K1: per-block coarse hist + global fine hist ----------------
__global__ __launch_bounds__(PBLOCK) void p1_hist(const int4* __restrict__ mask4,
                                                  int* __restrict__ hist_c,
                                                  int* __restrict__ fhist) {
  __shared__ int cnt[1024];  // fine counts over this block's 2^24 window
  const int blk = blockIdx.x, tid = threadIdx.x;
  if (tid < 1024) cnt[tid] = 0;
  __syncthreads();
  const int base4 = blk * (CHUNK / 4);
  #pragma unroll 4
  for (int k = 0; k < ITERS; ++k) {
    int4 m = mask4[base4 + k * PBLOCK + tid];
    atomicAdd(&cnt[m.x >> FB_SHIFT], 1);  // m.* < 2^24 -> index < 1024
    atomicAdd(&cnt[m.y >> FB_SHIFT], 1);
    atomicAdd(&cnt[m.z >> FB_SHIFT], 1);
    atomicAdd(&cnt[m.w >> FB_SHIFT], 1);
  }
  __syncthreads();
  const int boff = (blk * CHUNK) & ~(FLAT_IN - 1);
  const int f0   = boff >> FB_SHIFT;   // multiple of 256
  const int cb0  = f0 >> 2;
  for (int j = tid; j < 1024; j += PBLOCK)
    if (cnt[j]) atomicAdd(&fhist[f0 + j], cnt[j]);
  for (int j = tid; j < NBC_PAD; j += PBLOCK) {
    int v = 0;
    int jj = j - cb0;
    if (jj >= 0 && jj < 256)
      v = cnt[4 * jj] + cnt[4 * jj + 1] + cnt[4 * jj + 2] + cnt[4 * jj + 3];
    hist_c[blk * NBC_PAD + j] = v;
  }
}

// ---------------- K2a: segment sums over coarse hist block rows ----------------
__global__ __launch_bounds__(256) void p2_segsum(const int* __restrict__ hist,
                                                 int* __restrict__ segsum) {
  int b = blockIdx.x * 256 + threadIdx.x;
  int seg = blockIdx.y;
  const int* p = hist + (size_t)(seg * SEG_ROWS) * NBC_PAD + b;
  int s = 0;
  #pragma unroll 4
  for (int k = 0; k < SEG_ROWS; ++k) s += p[(size_t)k * NBC_PAD];
  segsum[seg * NBC_PAD + b] = s;
}

// ---------------- K2b: coarse bucket totals + exclusive scan -> bbase_c ----------
__global__ __launch_bounds__(256) void p2_scan_c(const int* __restrict__ segsum,
                                                 int* __restrict__ bbase) {
  __shared__ int tot[NBC_PAD];
  __shared__ int partial[256];
  const int t = threadIdx.x;
  for (int j = t; j < NBC_PAD; j += 256) {
    int s = 0;
    #pragma unroll
    for (int g = 0; g < SEGS; ++g) s += segsum[g * NBC_PAD + j];
    tot[j] = s;
  }
  __syncthreads();
  int local = 0;
  #pragma unroll
  for (int k = 0; k < NBC_PAD / 256; ++k) local += tot[t * (NBC_PAD / 256) + k];
  partial[t] = local;
  __syncthreads();
  for (int off = 1; off < 256; off <<= 1) {
    int tmp = (t >= off) ? partial[t - off] : 0;
    __syncthreads();
    partial[t] += tmp;
    __syncthreads();
  }
  int run = partial[t] - local;
  #pragma unroll
  for (int k = 0; k < NBC_PAD / 256; ++k) {
    int b = t * (NBC_PAD / 256) + k;
    bbase[b] = run;
    run += tot[b];
  }
  if (t == 255) bbase[NBC_PAD] = run;  // == N_ELEMS
}

// ---------------- K2c: expand coarse hist in place to per-(block,cb) offsets ----
__global__ __launch_bounds__(256) void p2_expand(int* __restrict__ hist,
                                                 const int* __restrict__ segsum) {
  int b = blockIdx.x * 256 + threadIdx.x;
  int seg = blockIdx.y;
  int run = 0;
  for (int g = 0; g < seg; ++g) run += segsum[g * NBC_PAD + b];
  int* p = hist + (size_t)(seg * SEG_ROWS) * NBC_PAD + b;
  for (int k = 0; k < SEG_ROWS; ++k) {
    int v = p[(size_t)k * NBC_PAD];
    p[(size_t)k * NBC_PAD] = run;
    run += v;
  }
}

// ---------------- K2d: fine totals -> exclusive scan -> bbase_f ----------------
__global__ __launch_bounds__(256) void p2_scan_f(const int* __restrict__ fhist,
                                                 int* __restrict__ bbase) {
  __shared__ int tot[NBF];
  __shared__ int partial[256];
  const int t = threadIdx.x;
  for (int j = t; j < NBF; j += 256) tot[j] = fhist[j];
  __syncthreads();
  int local = 0;
  #pragma unroll
  for (int k = 0; k < NBF / 256; ++k) local += tot[t * (NBF / 256) + k];
  partial[t] = local;
  __syncthreads();
  for (int off = 1; off < 256; off <<= 1) {
    int tmp = (t >= off) ? partial[t - off] : 0;
    __syncthreads();
    partial[t] += tmp;
    __syncthreads();
  }
  int run = partial[t] - local;
  #pragma unroll
  for (int k = 0; k < NBF / 256; ++k) {
    int b = t * (NBF / 256) + k;
    bbase[b] = run;
    run += tot[b];
  }
  if (t == 255) bbase[NBF] = run;  // == N_ELEMS
}

// ---------------- K3: coarse place (256 runs/block -> 1 MB/XCD open lines) ------
__global__ __launch_bounds__(PBLOCK) void p3a_place(const int4* __restrict__ mask4,
                                                    const float4* __restrict__ upd4,
                                                    const int* __restrict__ hist_c,
                                                    const int* __restrict__ bbase_c,
                                                    int2* __restrict__ pout) {
  __shared__ int cnt[256];
  __shared__ int rowbase[256];
  const int blk = blockIdx.x, tid = threadIdx.x;
  const int boff = (blk * CHUNK) & ~(FLAT_IN - 1);
  const int cb0 = boff >> CB_SHIFT;
  if (tid < 256) {
    cnt[tid] = 0;
    rowbase[tid] = bbase_c[cb0 + tid] + hist_c[blk * NBC_PAD + cb0 + tid];
  }
  __syncthreads();
  const int base4 = blk * (CHUNK / 4);
  #pragma unroll 2
  for (int k = 0; k < ITERS; ++k) {
    int j4 = base4 + k * PBLOCK + tid;
    int4 m = mask4[j4];
    float4 u = upd4[j4];
    {
      int b = m.x >> CB_SHIFT; int r = atomicAdd(&cnt[b], 1);
      pout[rowbase[b] + r] = make_int2(m.x + boff, __float_as_int(u.x));
    }
    {
      int b = m.y >> CB_SHIFT; int r = atomicAdd(&cnt[b], 1);
      pout[rowbase[b] + r] = make_int2(m.y + boff, __float_as_int(u.y));
    }
    {
      int b = m.z >> CB_SHIFT; int r = atomicAdd(&cnt[b], 1);
      pout[rowbase[b] + r] = make_int2(m.z + boff, __float_as_int(u.z));
    }
    {
      int b = m.w >> CB_SHIFT; int r = atomicAdd(&cnt[b], 1);
      pout[rowbase[b] + r] = make_int2(m.w + boff, __float_as_int(u.w));
    }
  }
}

// ---------------- K4: fine place within one coarse bucket -----------------------
// Wave-aggregated tickets: 2-ballot match on f&3 (valid: all pairs in this
// block share the coarse bucket), leader-only LDS atomic, rank via popcount.
__device__ __forceinline__ void pushA(int idx, int val, int* cnt, const int* fb,
                                      int2* __restrict__ pout) {
  int f = (idx >> FB_SHIFT) & 3;
  unsigned long long act = __ballot(1);
  unsigned long long b0 = __ballot(f & 1);
  unsigned long long b1 = __ballot(f & 2);
  unsigned long long mf = ((f & 1) ? b0 : ~b0) & ((f & 2) ? b1 : ~b1) & act;
  int lane = threadIdx.x & 63;
  int rank = __popcll(mf & ((1ull << lane) - 1ull));
  int leader = __ffsll((unsigned long long)mf) - 1;
  int r0 = 0;
  if (lane == leader) r0 = atomicAdd(&cnt[f], __popcll(mf));
  r0 = __shfl(r0, leader);
  pout[fb[f] + r0 + rank] = make_int2(idx, val);
}

__global__ __launch_bounds__(512) void p3b_fine(const int2* __restrict__ pin,
                                                const int* __restrict__ bbase_c,
                                                const int* __restrict__ bbase_f,
                                                int2* __restrict__ pout) {
  __shared__ int cnt[4];
  __shared__ int fb[4];
  const int cb = blockIdx.x, tid = threadIdx.x;
  if (tid < 4) {
    cnt[tid] = 0;
    fb[tid] = bbase_f[cb * 4 + tid];
  }
  __syncthreads();
  const int s = bbase_c[cb], e = bbase_c[cb + 1];
  const int s4 = (s + 1) & ~1;
  if ((s & 1) && s < e && tid == 0) {
    int2 p = pin[s];
    int f = (p.x >> FB_SHIFT) & 3;
    int r = atomicAdd(&cnt[f], 1);
    pout[fb[f] + r] = p;
  }
  const int n2 = (e > s4) ? ((e - s4) >> 1) : 0;
  const int4* pv = (const int4*)(pin + s4);
  for (int i = tid; i < n2; i += 512) {
    int4 q = pv[i];
    pushA(q.x, q.y, cnt, fb, pout);
    pushA(q.z, q.w, cnt, fb, pout);
  }
  if ((e > s4) && ((e - s4) & 1) && tid == 0) {
    int2 p = pin[e - 1];
    int f = (p.x >> FB_SHIFT) & 3;
    int r = atomicAdd(&cnt[f], 1);
    pout[fb[f] + r] = p;
  }
}

// ---------------- K5: apply one fine bucket via LDS, store window ----------------
__global__ __launch_bounds__(256) void p4_apply(const int2* __restrict__ pairs,
                                                const int* __restrict__ bbase,
                                                float* __restrict__ out) {
  __shared__ float win[BKT_SIZE];  // 64 KB -> 2 blocks/CU
  const int bkt = blockIdx.x, tid = threadIdx.x;
  floatx4* w4 = (floatx4*)win;
  floatx4 z = {0.f, 0.f, 0.f, 0.f};
  #pragma unroll
  for (int k = 0; k < BKT_SIZE / 1024; ++k) w4[k * 256 + tid] = z;
  __syncthreads();
  const int s = bbase[bkt], e = bbase[bkt + 1];
  const int s4 = (s + 1) & ~1;
  if ((s & 1) && s < e && tid == 0) {
    int2 p = pairs[s];
    atomicAdd(&win[p.x & (BKT_SIZE - 1)], __int_as_float(p.y));
  }
  const int n2 = (e > s4) ? ((e - s4) >> 1) : 0;
  const int4* pv = (const int4*)(pairs + s4);
  for (int i = tid; i < n2; i += 256) {
    int4 q = pv[i];
    atomicAdd(&win[q.x & (BKT_SIZE - 1)], __int_as_float(q.y));
    atomicAdd(&win[q.z & (BKT_SIZE - 1)], __int_as_float(q.w));
  }
  if ((e > s4) && ((e - s4) & 1) && tid == 0) {
    int2 p = pairs[e - 1];
    atomicAdd(&win[p.x & (BKT_SIZE - 1)], __int_as_float(p.y));
  }
  __syncthreads();
  floatx4* o4 = (floatx4*)(out + (size_t)bkt * BKT_SIZE);
  #pragma unroll
  for (int k = 0; k < BKT_SIZE / 1024; ++k)
    __builtin_nontemporal_store(w4[k * 256 + tid], o4 + k * 256 + tid);
}

// ---------------- fallback: R1 atomic scatter ----------------
__global__ __launch_bounds__(256) void scatter_add4_kernel(
    const float4* __restrict__ upd4, const int4* __restrict__ msk4,
    float* __restrict__ out, int n4) {
  int j = blockIdx.x * blockDim.x + threadIdx.x;
  if (j >= n4) return;
  float4 u = upd4[j];
  int4 m = msk4[j];
  int base = (j * 4) & ~(FLAT_IN - 1);
  unsafeAtomicAdd(out + (base + m.x), u.x);
  unsafeAtomicAdd(out + (base + m.y), u.y);
  unsafeAtomicAdd(out + (base + m.z), u.z);
  unsafeAtomicAdd(out + (base + m.w), u.w);
}

extern "C" void kernel_launch(void* const* d_in, const int* in_sizes, int n_in,
                              void* d_out, int out_size, void* d_ws, size_t ws_size,
                              hipStream_t stream) {
  const float* updates = (const float*)d_in[0];
  const int*   mask    = (const int*)d_in[1];
  float*       out     = (float*)d_out;
  const int n = in_sizes[0];

  const bool fast = (n == N_ELEMS) && (out_size == OUT_TOTAL) && (ws_size >= WS_NEEDED);

  if (!fast) {
    int n4z = out_size / 4;
    zero_kernel<<<(n4z + 2047) / 2048, 256, 0, stream>>>((floatx4*)d_out, n4z);
    int n4 = n / 4;
    scatter_add4_kernel<<<(n4 + 255) / 256, 256, 0, stream>>>(
        (const float4*)updates, (const int4*)mask, out, n4);
    return;
  }

  char* ws = (char*)d_ws;
  int2* pairs_f = (int2*)(ws + WS_PAIRS);        // fine-sorted pairs (pass 2 out)
  int*  hist_c  = (int*)(ws + WS_HISTC);
  int*  segsum  = (int*)(ws + WS_SEGC);
  int*  bbase_c = (int*)(ws + WS_BBC);
  int*  fhist   = (int*)(ws + WS_FH);
  int*  bbase_f = (int*)(ws + WS_BBF);
  int2* pairs_c = (int2*)(out + OUT_WIN);        // coarse-sorted pairs in out TAIL

  // zero global fine hist (11 KB)
  zero_kernel<<<1, 256, 0, stream>>>((floatx4*)fhist, NBF / 4);
  p1_hist<<<NBLK, PBLOCK, 0, stream>>>((const int4*)mask, hist_c, fhist);
  p2_segsum<<<dim3(NBC_PAD / 256, SEGS), 256, 0, stream>>>(hist_c, segsum);
  p2_scan_c<<<1, 256, 0, stream>>>(segsum, bbase_c);
  p2_expand<<<dim3(NBC_PAD / 256, SEGS), 256, 0, stream>>>(hist_c, segsum);
  p2_scan_f<<<1, 256, 0, stream>>>(fhist, bbase_f);
  // pass 1: coarse partition into out tail
  p3a_place<<<NBLK, PBLOCK, 0, stream>>>((const int4*)mask, (const float4*)updates,
                                         hist_c, bbase_c, pairs_c);
  // pass 2: fine partition (one block owns one coarse bucket = 4 fine buckets)
  p3b_fine<<<NBC, 512, 0, stream>>>(pairs_c, bbase_c, bbase_f, pairs_f);
  // now the tail scratch is dead -> zero it: [OUT_WIN, OUT_TOTAL), 352 MB
  {
    int n4 = (OUT_TOTAL - OUT_WIN) / 4;
    zero_kernel<<<5376, 256, 0, stream>>>((floatx4*)(out + OUT_WIN), n4);
  }
  p4_apply<<<NBF, 256, 0, stream>>>(pairs_f, bbase_f, out);
}

// Round 2
// 1109.294 us; speedup vs baseline: 1.0991x; 1.0991x over previous
//
#include <hip/hip_runtime.h>

// MaxUnpooling2D scatter-add — round 6: coarse-only radix + half-window apply.
//
// R5 post-mortem: total unchanged (1212 -> 1219 us). The fine pass (p3b)
// spent as much as the amplification it saved: the saved ~700 MB of
// partial-line writes was repurchased as a full extra pairs round-trip
// (268 W + 268 R) plus 10 dispatches of launch/sync overhead.
//
// R6: delete the fine level. A coarse bucket (2^16 floats = 256 KB) does
// not fit LDS, but HALF of one (2^15 floats = 128 KB) does, at 1 block/CU.
// p4c consumes coarse-sorted pairs directly: block h owns half-window h,
// reads coarse bucket h>>1's pair run, filters on idx bit 15 (discards
// half), LDS-atomics the rest, streams 128 KB out nontemporal.
//   - p3b + fine hist/scan deleted: net -268 MB (one extra coarse-pairs
//     read replaces a fine-pairs write+read).
//   - pairs now live in ws (fine slot freed), so the out tail is never
//     scratch -> p4c's grid covers ALL of OUT_TOTAL; tail blocks stream
//     zeros -> separate 352 MB zero-tail launch deleted.
//   - sibling half-windows (2cb, 2cb+1) are swizzled onto the same XCD
//     (dispatch is round-robin mod 8) so the 2nd read of a run L2-hits.
//   - p3a keeps the proven 256-runs/block geometry (1 MB/XCD open lines).
// Pipeline: 10 -> 6 dispatches, ~2.0 -> ~1.75 GB.

typedef float floatx4 __attribute__((ext_vector_type(4)));

constexpr int FLAT_IN   = 1 << 22;                 // 4,194,304
constexpr int N_ELEMS   = 8 * FLAT_IN;             // 33,554,432
constexpr int OUT_WIN   = 7 * FLAT_IN + (1 << 24); // 46,137,344
constexpr int OUT_TOTAL = 134217728;

constexpr int CB_SHIFT = 16;                  // coarse bucket: 64K floats
constexpr int NBC      = OUT_WIN >> CB_SHIFT; // 704
constexpr int NBC_PAD  = 768;                 // 3*256 for scan kernels

constexpr int AP_SHIFT = 15;                  // apply half-window: 32K floats = 128 KB LDS
constexpr int APW      = 1 << AP_SHIFT;
constexpr int NAP      = OUT_TOTAL >> AP_SHIFT; // 4096 (full output incl. tail)
constexpr int NAP_WIN  = OUT_WIN >> AP_SHIFT;   // 1408 (half-windows with pairs)

constexpr int PBLOCK   = 1024;                // threads, partition kernels
constexpr int CHUNK    = 131072;              // elems per p1/p3a block
constexpr int NBLK     = N_ELEMS / CHUNK;     // 256
constexpr int ITERS    = CHUNK / (4 * PBLOCK);// 32
constexpr int SEGS     = 8;
constexpr int SEG_ROWS = NBLK / SEGS;         // 32

// ---- workspace layout (bytes) ----
constexpr size_t WS_PAIRS  = 0;                                     // int2[N_ELEMS] = 268,435,456
constexpr size_t WS_HISTC  = 268435456;                             // int[NBLK*NBC_PAD]
constexpr size_t WS_SEGC   = WS_HISTC + (size_t)NBLK * NBC_PAD * 4; // int[SEGS*NBC_PAD]
constexpr size_t WS_BBC    = WS_SEGC + (size_t)SEGS * NBC_PAD * 4;  // int[NBC_PAD+1]
constexpr size_t WS_NEEDED = WS_BBC + (size_t)(NBC_PAD + 1) * 4;

// ---------------- K0: zero a float4 range (nontemporal) ----------------
__global__ __launch_bounds__(256) void zero_kernel(floatx4* __restrict__ p, int n4) {
  int i = blockIdx.x * 256 + threadIdx.x;
  int stride = gridDim.x * 256;
  floatx4 z = {0.f, 0.f, 0.f, 0.f};
  for (; i < n4; i += stride) __builtin_nontemporal_store(z, p + i);
}

// ---------------- K1: per-block coarse histogram ----------------
__global__ __launch_bounds__(PBLOCK) void p1_hist(const int4* __restrict__ mask4,
                                                  int* __restrict__ hist_c) {
  __shared__ int cnt[256];  // coarse counts over this block's 2^24 window
  const int blk = blockIdx.x, tid = threadIdx.x;
  if (tid < 256) cnt[tid] = 0;
  __syncthreads();
  const int base4 = blk * (CHUNK / 4);
  #pragma unroll 4
  for (int k = 0; k < ITERS; ++k) {
    int4 m = mask4[base4 + k * PBLOCK + tid];
    atomicAdd(&cnt[m.x >> CB_SHIFT], 1);  // m.* < 2^24 -> index < 256
    atomicAdd(&cnt[m.y >> CB_SHIFT], 1);
    atomicAdd(&cnt[m.z >> CB_SHIFT], 1);
    atomicAdd(&cnt[m.w >> CB_SHIFT], 1);
  }
  __syncthreads();
  const int cb0 = ((blk * CHUNK) & ~(FLAT_IN - 1)) >> CB_SHIFT;
  for (int j = tid; j < NBC_PAD; j += PBLOCK) {
    int jj = j - cb0;
    hist_c[blk * NBC_PAD + j] = (jj >= 0 && jj < 256) ? cnt[jj] : 0;
  }
}

// ---------------- K2a: segment sums over coarse hist block rows ----------------
__global__ __launch_bounds__(256) void p2_segsum(const int* __restrict__ hist,
                                                 int* __restrict__ segsum) {
  int b = blockIdx.x * 256 + threadIdx.x;
  int seg = blockIdx.y;
  const int* p = hist + (size_t)(seg * SEG_ROWS) * NBC_PAD + b;
  int s = 0;
  #pragma unroll 4
  for (int k = 0; k < SEG_ROWS; ++k) s += p[(size_t)k * NBC_PAD];
  segsum[seg * NBC_PAD + b] = s;
}

// ---------------- K2b: coarse bucket totals + exclusive scan -> bbase_c ----------
__global__ __launch_bounds__(256) void p2_scan_c(const int* __restrict__ segsum,
                                                 int* __restrict__ bbase) {
  __shared__ int tot[NBC_PAD];
  __shared__ int partial[256];
  const int t = threadIdx.x;
  for (int j = t; j < NBC_PAD; j += 256) {
    int s = 0;
    #pragma unroll
    for (int g = 0; g < SEGS; ++g) s += segsum[g * NBC_PAD + j];
    tot[j] = s;
  }
  __syncthreads();
  int local = 0;
  #pragma unroll
  for (int k = 0; k < NBC_PAD / 256; ++k) local += tot[t * (NBC_PAD / 256) + k];
  partial[t] = local;
  __syncthreads();
  for (int off = 1; off < 256; off <<= 1) {
    int tmp = (t >= off) ? partial[t - off] : 0;
    __syncthreads();
    partial[t] += tmp;
    __syncthreads();
  }
  int run = partial[t] - local;
  #pragma unroll
  for (int k = 0; k < NBC_PAD / 256; ++k) {
    int b = t * (NBC_PAD / 256) + k;
    bbase[b] = run;
    run += tot[b];
  }
  if (t == 255) bbase[NBC_PAD] = run;  // == N_ELEMS
}

// ---------------- K2c: expand coarse hist in place to per-(block,cb) offsets ----
__global__ __launch_bounds__(256) void p2_expand(int* __restrict__ hist,
                                                 const int* __restrict__ segsum) {
  int b = blockIdx.x * 256 + threadIdx.x;
  int seg = blockIdx.y;
  int run = 0;
  for (int g = 0; g < seg; ++g) run += segsum[g * NBC_PAD + b];
  int* p = hist + (size_t)(seg * SEG_ROWS) * NBC_PAD + b;
  for (int k = 0; k < SEG_ROWS; ++k) {
    int v = p[(size_t)k * NBC_PAD];
    p[(size_t)k * NBC_PAD] = run;
    run += v;
  }
}

// ---------------- K3: coarse place (256 runs/block -> 1 MB/XCD open lines) ------
__global__ __launch_bounds__(PBLOCK) void p3a_place(const int4* __restrict__ mask4,
                                                    const float4* __restrict__ upd4,
                                                    const int* __restrict__ hist_c,
                                                    const int* __restrict__ bbase_c,
                                                    int2* __restrict__ pout) {
  __shared__ int cnt[256];
  __shared__ int rowbase[256];
  const int blk = blockIdx.x, tid = threadIdx.x;
  const int boff = (blk * CHUNK) & ~(FLAT_IN - 1);
  const int cb0 = boff >> CB_SHIFT;
  if (tid < 256) {
    cnt[tid] = 0;
    rowbase[tid] = bbase_c[cb0 + tid] + hist_c[blk * NBC_PAD + cb0 + tid];
  }
  __syncthreads();
  const int base4 = blk * (CHUNK / 4);
  #pragma unroll 2
  for (int k = 0; k < ITERS; ++k) {
    int j4 = base4 + k * PBLOCK + tid;
    int4 m = mask4[j4];
    float4 u = upd4[j4];
    {
      int b = m.x >> CB_SHIFT; int r = atomicAdd(&cnt[b], 1);
      pout[rowbase[b] + r] = make_int2(m.x + boff, __float_as_int(u.x));
    }
    {
      int b = m.y >> CB_SHIFT; int r = atomicAdd(&cnt[b], 1);
      pout[rowbase[b] + r] = make_int2(m.y + boff, __float_as_int(u.y));
    }
    {
      int b = m.z >> CB_SHIFT; int r = atomicAdd(&cnt[b], 1);
      pout[rowbase[b] + r] = make_int2(m.z + boff, __float_as_int(u.z));
    }
    {
      int b = m.w >> CB_SHIFT; int r = atomicAdd(&cnt[b], 1);
      pout[rowbase[b] + r] = make_int2(m.w + boff, __float_as_int(u.w));
    }
  }
}

// ---------------- K4: apply one 2^15-float half-window (128 KB LDS) -------------
// Block h covers out[h*APW, (h+1)*APW). For h < NAP_WIN it scans coarse
// bucket (h>>1)'s pair run and keeps entries whose idx bit 15 == h&1.
// For h >= NAP_WIN (the tail, never touched by pairs) it streams zeros.
__global__ __launch_bounds__(1024) void p4c_apply(const int2* __restrict__ pairs,
                                                  const int* __restrict__ bbase,
                                                  float* __restrict__ out) {
  __shared__ float win[APW];  // 128 KB -> 1 block/CU
  const int tid = threadIdx.x;
  // XCD-pairing swizzle: siblings (2cb, 2cb+1) land on the same XCD
  // (dispatch round-robins blockIdx % 8), so the second scan of a pair
  // run hits that XCD's L2. Bijective within each 16-block group.
  const int b = blockIdx.x;
  const int h = (b & ~15) | ((b & 7) << 1) | ((b >> 3) & 1);
  floatx4* w4 = (floatx4*)win;
  floatx4 z = {0.f, 0.f, 0.f, 0.f};
  #pragma unroll
  for (int k = 0; k < APW / 4096; ++k) w4[k * 1024 + tid] = z;  // 8 stores
  if (h < NAP_WIN) {
    __syncthreads();
    const int cb = h >> 1;
    const int sel = h & 1;
    const int s = bbase[cb], e = bbase[cb + 1];
    const int s4 = (s + 1) & ~1;  // first even pair index (int4-aligned)
    if ((s & 1) && s < e && tid == 0) {
      int2 p = pairs[s];
      if (((p.x >> AP_SHIFT) & 1) == sel)
        atomicAdd(&win[p.x & (APW - 1)], __int_as_float(p.y));
    }
    const int n2 = (e > s4) ? ((e - s4) >> 1) : 0;
    const int4* pv = (const int4*)(pairs + s4);
    for (int i = tid; i < n2; i += 1024) {
      int4 q = pv[i];
      if (((q.x >> AP_SHIFT) & 1) == sel)
        atomicAdd(&win[q.x & (APW - 1)], __int_as_float(q.y));
      if (((q.z >> AP_SHIFT) & 1) == sel)
        atomicAdd(&win[q.z & (APW - 1)], __int_as_float(q.w));
    }
    if ((e > s4) && ((e - s4) & 1) && tid == 0) {
      int2 p = pairs[e - 1];
      if (((p.x >> AP_SHIFT) & 1) == sel)
        atomicAdd(&win[p.x & (APW - 1)], __int_as_float(p.y));
    }
    __syncthreads();
  }
  floatx4* o4 = (floatx4*)(out + (size_t)h * APW);
  #pragma unroll
  for (int k = 0; k < APW / 4096; ++k)
    __builtin_nontemporal_store(w4[k * 1024 + tid], o4 + k * 1024 + tid);
}

// ---------------- fallback: R1 atomic scatter ----------------
__global__ __launch_bounds__(256) void scatter_add4_kernel(
    const float4* __restrict__ upd4, const int4* __restrict__ msk4,
    float* __restrict__ out, int n4) {
  int j = blockIdx.x * blockDim.x + threadIdx.x;
  if (j >= n4) return;
  float4 u = upd4[j];
  int4 m = msk4[j];
  int base = (j * 4) & ~(FLAT_IN - 1);
  unsafeAtomicAdd(out + (base + m.x), u.x);
  unsafeAtomicAdd(out + (base + m.y), u.y);
  unsafeAtomicAdd(out + (base + m.z), u.z);
  unsafeAtomicAdd(out + (base + m.w), u.w);
}

extern "C" void kernel_launch(void* const* d_in, const int* in_sizes, int n_in,
                              void* d_out, int out_size, void* d_ws, size_t ws_size,
                              hipStream_t stream) {
  const float* updates = (const float*)d_in[0];
  const int*   mask    = (const int*)d_in[1];
  float*       out     = (float*)d_out;
  const int n = in_sizes[0];

  const bool fast = (n == N_ELEMS) && (out_size == OUT_TOTAL) && (ws_size >= WS_NEEDED);

  if (!fast) {
    int n4z = out_size / 4;
    zero_kernel<<<(n4z + 2047) / 2048, 256, 0, stream>>>((floatx4*)d_out, n4z);
    int n4 = n / 4;
    scatter_add4_kernel<<<(n4 + 255) / 256, 256, 0, stream>>>(
        (const float4*)updates, (const int4*)mask, out, n4);
    return;
  }

  char* ws = (char*)d_ws;
  int2* pairs   = (int2*)(ws + WS_PAIRS);
  int*  hist_c  = (int*)(ws + WS_HISTC);
  int*  segsum  = (int*)(ws + WS_SEGC);
  int*  bbase_c = (int*)(ws + WS_BBC);

  p1_hist<<<NBLK, PBLOCK, 0, stream>>>((const int4*)mask, hist_c);
  p2_segsum<<<dim3(NBC_PAD / 256, SEGS), 256, 0, stream>>>(hist_c, segsum);
  p2_scan_c<<<1, 256, 0, stream>>>(segsum, bbase_c);
  p2_expand<<<dim3(NBC_PAD / 256, SEGS), 256, 0, stream>>>(hist_c, segsum);
  p3a_place<<<NBLK, PBLOCK, 0, stream>>>((const int4*)mask, (const float4*)updates,
                                         hist_c, bbase_c, pairs);
  p4c_apply<<<NAP, 1024, 0, stream>>>(pairs, bbase_c, out);
}